// Round 1
// baseline (190.955 us; speedup 1.0000x reference)
//
#include <hip/hip_runtime.h>

#define NBASE 15
#define CDIM  4096
#define BATCH 512
#define NP    16           // batch chunks
#define BPC   (BATCH/NP)   // 32 batches per chunk

// Module-scope scratch: fully overwritten every call (no cross-call state
// dependence), avoids relying on ws_size. ~3.9 MB.
__device__ float  g_partial[NP][NBASE][CDIM];
__device__ double g_stats[2][NBASE];   // [0]=sub_mean, [1]=sub_std

// ---- k1: partial batch sums.  grid = 15 * 4 * 16 = 960 blocks ----
// block decodes (n, cc, p): p = batch chunk, cc = 1024-col chunk.
__global__ __launch_bounds__(256) void k1_partial(const float4* __restrict__ in) {
    const int id = blockIdx.x;
    const int p  = id & 15;          // batch chunk
    const int cc = (id >> 4) & 3;    // column chunk (1024 floats = 256 float4)
    const int n  = id >> 6;          // base index 0..14
    const int c4 = cc * 256 + threadIdx.x;   // float4 column
    const int row_f4 = CDIM / 4;             // 1024 float4 per row

    float4 acc = make_float4(0.f, 0.f, 0.f, 0.f);
    const int b0 = p * BPC;
    #pragma unroll 4
    for (int i = 0; i < BPC; ++i) {
        const int row = (b0 + i) * NBASE + n;
        float4 v = in[(size_t)row * row_f4 + c4];
        acc.x += v.x; acc.y += v.y; acc.z += v.z; acc.w += v.w;
    }
    float4* out4 = reinterpret_cast<float4*>(&g_partial[p][n][0]);
    out4[c4] = acc;
}

// ---- k2: per-n mean/std over C.  grid = 15 blocks ----
__global__ __launch_bounds__(256) void k2_stats() {
    const int n = blockIdx.x;
    double sm = 0.0, sm2 = 0.0;
    for (int c = threadIdx.x; c < CDIM; c += 256) {
        float s = 0.f;
        #pragma unroll
        for (int p = 0; p < NP; ++p) s += g_partial[p][n][c];
        const double m = (double)s * (1.0 / BATCH);
        sm += m; sm2 += m * m;
    }
    __shared__ double red0[256];
    __shared__ double red1[256];
    red0[threadIdx.x] = sm; red1[threadIdx.x] = sm2;
    __syncthreads();
    for (int off = 128; off > 0; off >>= 1) {
        if ((int)threadIdx.x < off) {
            red0[threadIdx.x] += red0[threadIdx.x + off];
            red1[threadIdx.x] += red1[threadIdx.x + off];
        }
        __syncthreads();
    }
    if (threadIdx.x == 0) {
        const double S = red0[0], S2 = red1[0];
        const double mean = S / CDIM;
        const double var  = (S2 - S * S / CDIM) / (CDIM - 1);   // ddof=1
        g_stats[0][n] = mean;
        g_stats[1][n] = sqrt(var);
    }
}

// ---- k3: group stats + pairwise loss, scalar (double) ----
__global__ void k3_loss(float* __restrict__ out) {
    if (threadIdx.x != 0 || blockIdx.x != 0) return;
    const int G = 6;
    const int off[G] = {0, 3, 5, 6, 10, 12};
    const int len[G] = {3, 2, 1, 4, 2, 3};
    double ss[G], mn[G], ms[G];
    for (int g = 0; g < G; ++g) {
        const int o = off[g], L = len[g];
        if (L == 1) {
            ss[g] = g_stats[1][o];
            mn[g] = g_stats[0][o];
            ms[g] = g_stats[0][o];
        } else {
            double sm = 0.0, st = 0.0;
            for (int k = 0; k < L; ++k) { sm += g_stats[0][o + k]; st += g_stats[1][o + k]; }
            sm /= L; st /= L;
            double vm = 0.0, vs = 0.0;
            for (int k = 0; k < L; ++k) {
                const double dm = g_stats[0][o + k] - sm; vm += dm * dm;
                const double ds = g_stats[1][o + k] - st; vs += ds * ds;
            }
            mn[g] = sm;
            ms[g] = sqrt(vm / (L - 1));   // mean_sum = std of group means (ddof=1)
            ss[g] = sqrt(vs / (L - 1));   // ss       = std of group stds  (ddof=1)
        }
    }
    double loss = 0.0;
    for (int i = 0; i < G; ++i) {
        double sl = 5e-5;
        for (int j = i + 1; j < G; ++j) {
            const double ds = ss[i] - ss[j];
            const double dm = mn[i] - mn[j];
            sl += exp(ds * ds) + exp(dm * dm);   // MEAN_STD = 1.0
        }
        loss += log(1.0 + ms[i] / (sl + ms[i]));
    }
    out[0] = (float)loss;
}

extern "C" void kernel_launch(void* const* d_in, const int* in_sizes, int n_in,
                              void* d_out, int out_size, void* d_ws, size_t ws_size,
                              hipStream_t stream) {
    const float4* in = (const float4*)d_in[0];
    float* out = (float*)d_out;
    hipLaunchKernelGGL(k1_partial, dim3(NBASE * 4 * NP), dim3(256), 0, stream, in);
    hipLaunchKernelGGL(k2_stats,   dim3(NBASE),          dim3(256), 0, stream);
    hipLaunchKernelGGL(k3_loss,    dim3(1),              dim3(64),  0, stream, out);
}

// Round 4
// 185.266 us; speedup vs baseline: 1.0307x; 1.0307x over previous
//
#include <hip/hip_runtime.h>

#define NBASE 15
#define CDIM  4096
#define C4    (CDIM/4)     // 1024 float4 per row
#define BATCH 512
#define NP    32           // batch chunks
#define BPC   (BATCH/NP)   // 16 batches per chunk

// Module-scope scratch, fully overwritten every call. ~7.9 MB.
__device__ float4 g_partial4[NP][NBASE][C4];
__device__ double g_red[NBASE][4][2];   // per (n, col-chunk): [0]=sum(mean), [1]=sum(mean^2)

// pair index tables for the 6-group upper triangle (15 pairs)
__device__ __constant__ int c_pi[15] = {0,0,0,0,0,1,1,1,1,2,2,2,3,3,4};
__device__ __constant__ int c_pj[15] = {1,2,3,4,5,2,3,4,5,3,4,5,4,5,5};

// ---- k1: partial batch sums. grid = 15 * 4 * 32 = 1920 blocks ----
__global__ __launch_bounds__(256) void k1_partial(const float4* __restrict__ in) {
    const int id = blockIdx.x;
    const int p  = id & 31;          // batch chunk
    const int cc = (id >> 5) & 3;    // column chunk (256 float4)
    const int n  = id >> 7;          // base index 0..14
    const int c4 = cc * 256 + threadIdx.x;

    float4 acc = make_float4(0.f, 0.f, 0.f, 0.f);
    const int b0 = p * BPC;
    #pragma unroll
    for (int i = 0; i < BPC; ++i) {
        const int row = (b0 + i) * NBASE + n;
        float4 v = in[(size_t)row * C4 + c4];
        acc.x += v.x; acc.y += v.y; acc.z += v.z; acc.w += v.w;
    }
    g_partial4[p][n][c4] = acc;
}

// ---- k2: per-(n, col-chunk) partial stats. grid = 15*4 = 60 blocks ----
__global__ __launch_bounds__(256) void k2_stats() {
    const int n  = blockIdx.x >> 2;
    const int cc = blockIdx.x & 3;
    const int c4 = cc * 256 + threadIdx.x;

    float4 s = make_float4(0.f, 0.f, 0.f, 0.f);
    #pragma unroll
    for (int p = 0; p < NP; ++p) {
        float4 v = g_partial4[p][n][c4];
        s.x += v.x; s.y += v.y; s.z += v.z; s.w += v.w;
    }
    const double inv = 1.0 / BATCH;
    const double m0 = (double)s.x * inv, m1 = (double)s.y * inv;
    const double m2 = (double)s.z * inv, m3 = (double)s.w * inv;
    double sm  = m0 + m1 + m2 + m3;
    double sm2 = m0*m0 + m1*m1 + m2*m2 + m3*m3;

    __shared__ double red0[256];
    __shared__ double red1[256];
    red0[threadIdx.x] = sm; red1[threadIdx.x] = sm2;
    __syncthreads();
    for (int off = 128; off > 0; off >>= 1) {
        if ((int)threadIdx.x < off) {
            red0[threadIdx.x] += red0[threadIdx.x + off];
            red1[threadIdx.x] += red1[threadIdx.x + off];
        }
        __syncthreads();
    }
    if (threadIdx.x == 0) {
        g_red[n][cc][0] = red0[0];
        g_red[n][cc][1] = red1[0];
    }
}

// ---- k3: finalize stats + group math + loss. 1 block x 64 threads ----
__global__ __launch_bounds__(64) void k3_loss(float* __restrict__ out) {
    __shared__ double sub_mean[NBASE], sub_std[NBASE];
    __shared__ double mn[6], ms[6], ssg[6];
    __shared__ double pairv[15];
    __shared__ double terms[6];
    const int t = threadIdx.x;

    if (t < NBASE) {
        double S = 0.0, S2 = 0.0;
        #pragma unroll
        for (int cc = 0; cc < 4; ++cc) { S += g_red[t][cc][0]; S2 += g_red[t][cc][1]; }
        sub_mean[t] = S / CDIM;
        sub_std[t]  = sqrt((S2 - S * S / CDIM) / (CDIM - 1));   // ddof=1
    }
    __syncthreads();

    if (t < 6) {
        const int off[6] = {0, 3, 5, 6, 10, 12};
        const int len[6] = {3, 2, 1, 4, 2, 3};
        const int o = off[t], L = len[t];
        if (L == 1) {
            ssg[t] = sub_std[o];
            mn[t]  = sub_mean[o];
            ms[t]  = sub_mean[o];
        } else {
            double sm = 0.0, st = 0.0;
            for (int k = 0; k < L; ++k) { sm += sub_mean[o + k]; st += sub_std[o + k]; }
            sm /= L; st /= L;
            double vm = 0.0, vs = 0.0;
            for (int k = 0; k < L; ++k) {
                const double dm = sub_mean[o + k] - sm; vm += dm * dm;
                const double ds = sub_std[o + k]  - st; vs += ds * ds;
            }
            mn[t]  = sm;
            ms[t]  = sqrt(vm / (L - 1));   // std of group means (ddof=1)
            ssg[t] = sqrt(vs / (L - 1));   // std of group stds  (ddof=1)
        }
    }
    __syncthreads();

    if (t < 15) {
        const double ds = ssg[c_pi[t]] - ssg[c_pj[t]];
        const double dm = mn[c_pi[t]]  - mn[c_pj[t]];
        pairv[t] = exp(ds * ds) + exp(dm * dm);   // MEAN_STD = 1.0
    }
    __syncthreads();

    if (t < 6) {
        double sl = 5e-5;
        for (int p = 0; p < 15; ++p)
            if (c_pi[p] == t) sl += pairv[p];
        terms[t] = log(1.0 + ms[t] / (sl + ms[t]));
    }
    __syncthreads();

    if (t == 0) {
        double loss = 0.0;
        #pragma unroll
        for (int g = 0; g < 6; ++g) loss += terms[g];
        out[0] = (float)loss;
    }
}

extern "C" void kernel_launch(void* const* d_in, const int* in_sizes, int n_in,
                              void* d_out, int out_size, void* d_ws, size_t ws_size,
                              hipStream_t stream) {
    const float4* in = (const float4*)d_in[0];
    float* out = (float*)d_out;
    hipLaunchKernelGGL(k1_partial, dim3(NBASE * 4 * NP), dim3(256), 0, stream, in);
    hipLaunchKernelGGL(k2_stats,   dim3(NBASE * 4),      dim3(256), 0, stream);
    hipLaunchKernelGGL(k3_loss,    dim3(1),              dim3(64),  0, stream, out);
}